// Round 1
// baseline (3128.864 us; speedup 1.0000x reference)
//
#include <hip/hip_runtime.h>
#include <math.h>

// Conv1D(k=2,F=64,relu) -> LSTM1(H=100, relu cell, seq) -> LSTM2 (last) ->
// Dense(3) -> softmax.  B=128, T=2048, T'=2047.
//
// Round-6 design (from round-5's 2-slot LDS ring, producer/consumer waves):
//  * DS-pipe relief: each dot-thread now owns TWO units (q, q+50) x 4 gates
//    with a FOUR-way K split (thread = (q in [0,50), s in [0,4))).  Operand
//    bytes read from LDS per step are halved (producer 6 ds_read_b128 vs 11,
//    consumer 7 vs 13) because each float4 read feeds 8 dot chains instead
//    of 4.  K is padded so quarters stay 16-B aligned:
//      X1 slot: [x(64) ; h1(100) ; pad(28)]      = 192 halves, quarter 96 B
//      X2 slot: [x2(100); pad12 ; h2(100); pad12] = 224 halves, quarter 112 B
//    Pads are zero in LDS AND in the f16 weight registers -> contribute 0.
//  * Cross-lane reduction moved off the DS pipe: ds_swizzle pairsum replaced
//    by a 2-round DPP quad_perm butterfly (0xB1 = xor1, 0x4E = xor2), pure
//    VALU.  All 4 quad lanes end with bitwise-identical sums (commutativity),
//    so the per-lane recurrent c-state stays consistent across lanes/steps.
//  * Everything else retained: one block per batch element, waves 0..3
//    conv+LSTM1 (producer), waves 4..7 LSTM2 one step behind (consumer),
//    2-slot LDS ring, one barrier per step, weights resident in h2 regs
//    (overflow to unified AGPR file as before).

typedef _Float16 h2 __attribute__((ext_vector_type(2)));

#define BB 128
#define TT 2048
#define TP 2047
#define HH 100
#define G4 400
#define FF 64

#define K1 192   // producer combined-K halves (x 64 + h 100 + pad 28)
#define K2 224   // consumer combined-K halves (x2 100 + pad 12 + h2 100 + pad 12)

#define L24(X) X(0) X(1) X(2) X(3) X(4) X(5) X(6) X(7) X(8) X(9) \
 X(10) X(11) X(12) X(13) X(14) X(15) X(16) X(17) X(18) X(19) \
 X(20) X(21) X(22) X(23)
#define L28(X) L24(X) X(24) X(25) X(26) X(27)

#define DW8(i) h2 wA##i, wB##i, wC##i, wD##i, wE##i, wF##i, wG##i, wH##i;

// producer combined column: K = [conv-x(64) ; U(100) ; pad(28)] -> 192
static __device__ __forceinline__ _Float16 pw(const float* __restrict__ W,
                                              const float* __restrict__ U,
                                              int c, int k) {
    float v = (k < FF) ? W[k * G4 + c] : (k < FF + HH ? U[(k - FF) * G4 + c] : 0.0f);
    return (_Float16)v;
}
// consumer combined column: K = [W(100) ; gap(12) ; U(100) ; pad(12)] -> 224
static __device__ __forceinline__ _Float16 cwf(const float* __restrict__ W,
                                               const float* __restrict__ U,
                                               int c, int k) {
    float v = (k < HH) ? W[k * G4 + c]
            : (k < 112 ? 0.0f : (k < 212 ? U[(k - 112) * G4 + c] : 0.0f));
    return (_Float16)v;
}

#define LWP8(i) { const int k = kb + 2 * (i); \
  wA##i = h2{pw(W,U,cA,k), pw(W,U,cA,k+1)}; \
  wB##i = h2{pw(W,U,cB,k), pw(W,U,cB,k+1)}; \
  wC##i = h2{pw(W,U,cC,k), pw(W,U,cC,k+1)}; \
  wD##i = h2{pw(W,U,cD,k), pw(W,U,cD,k+1)}; \
  wE##i = h2{pw(W,U,cE,k), pw(W,U,cE,k+1)}; \
  wF##i = h2{pw(W,U,cF,k), pw(W,U,cF,k+1)}; \
  wG##i = h2{pw(W,U,cG,k), pw(W,U,cG,k+1)}; \
  wH##i = h2{pw(W,U,cH,k), pw(W,U,cH,k+1)}; }

#define LWC8(i) { const int k = kb + 2 * (i); \
  wA##i = h2{cwf(W,U,cA,k), cwf(W,U,cA,k+1)}; \
  wB##i = h2{cwf(W,U,cB,k), cwf(W,U,cB,k+1)}; \
  wC##i = h2{cwf(W,U,cC,k), cwf(W,U,cC,k+1)}; \
  wD##i = h2{cwf(W,U,cD,k), cwf(W,U,cD,k+1)}; \
  wE##i = h2{cwf(W,U,cE,k), cwf(W,U,cE,k+1)}; \
  wF##i = h2{cwf(W,U,cF,k), cwf(W,U,cF,k+1)}; \
  wG##i = h2{cwf(W,U,cG,k), cwf(W,U,cG,k+1)}; \
  wH##i = h2{cwf(W,U,cH,k), cwf(W,U,cH,k+1)}; }

#define FD(w, x, acc) acc = __builtin_amdgcn_fdot2(w, x, acc, false)
#define B2(f) __builtin_bit_cast(h2, f)

// one float4 operand chunk feeds all 8 dot chains (2 units x 4 gates)
#define DOT8X(vs, i) { const h2 xx = B2(vs); \
  FD(wA##i, xx, zA); FD(wB##i, xx, zB); FD(wC##i, xx, zC); FD(wD##i, xx, zD); \
  FD(wE##i, xx, zE); FD(wF##i, xx, zF); FD(wG##i, xx, zG); FD(wH##i, xx, zH); }
#define DOT8(r, a0, a1, a2, a3) { const float4 v = vb[r]; \
  DOT8X(v.x, a0) DOT8X(v.y, a1) DOT8X(v.z, a2) DOT8X(v.w, a3) }

// 4-lane quad butterfly sum via DPP (VALU only, no DS pipe).
// 0xB1 = quad_perm [1,0,3,2] (xor 1), 0x4E = quad_perm [2,3,0,1] (xor 2).
// All 4 lanes produce bitwise-identical results (each final add is a+b vs b+a).
static __device__ __forceinline__ float qsum4(float z) {
    int p1 = __builtin_amdgcn_update_dpp(0, __builtin_bit_cast(int, z),
                                         0xB1, 0xF, 0xF, true);
    float s1 = z + __builtin_bit_cast(float, p1);
    int p2 = __builtin_amdgcn_update_dpp(0, __builtin_bit_cast(int, s1),
                                         0x4E, 0xF, 0xF, true);
    return s1 + __builtin_bit_cast(float, p2);
}
static __device__ __forceinline__ float sig(float z) {
    return 1.0f / (1.0f + __expf(-z));
}

__global__ __launch_bounds__(512, 2)
void fused_lstm_kernel(const float* __restrict__ s,       // [B,T]
                       const float* __restrict__ conv_w,  // [2,1,F]
                       const float* __restrict__ conv_b,  // [F]
                       const float* __restrict__ w1, const float* __restrict__ u1,
                       const float* __restrict__ b1,
                       const float* __restrict__ w2, const float* __restrict__ u2,
                       const float* __restrict__ b2,
                       const float* __restrict__ dw, const float* __restrict__ db,
                       float* __restrict__ out)           // [B,3]
{
    const int tid = threadIdx.x;
    const int b   = blockIdx.x;

    __shared__ float s_buf[TT];                        // 8 KB input row
    __shared__ __align__(16) _Float16 X1[2 * K1];      // producer operand ring
    __shared__ __align__(16) _Float16 X2[2 * K2];      // consumer operand ring

    for (int i = tid; i < TT; i += 512) s_buf[i] = s[(size_t)b * TT + i];
    if (tid < 2 * K1) X1[tid] = (_Float16)0.0f;        // pads stay 0 forever
    if (tid < 2 * K2) X2[tid] = (_Float16)0.0f;
    __syncthreads();                                   // (A)

    if (tid < 256) {
        // ================= PRODUCER waves: conv + LSTM1 =================
        const int rt  = tid;
        const int q   = (rt < 200) ? (rt >> 2) : 0;    // unit pair {q, q+50}
        const int sq  = rt & 3;                        // K-quarter
        const int cA = q,        cB = HH + q,       cC = 2*HH + q,      cD = 3*HH + q;
        const int cE = 50 + q,   cF = HH + 50 + q,  cG = 2*HH + 50 + q, cH = 3*HH + 50 + q;
        const float* W = w1;
        const float* U = u1;
        const int kb = sq * 48;                        // quarter base (halves), 96 B aligned

        L24(DW8)
        L24(LWP8)
        const float bA = b1[cA], bB = b1[cB], bC = b1[cC], bD = b1[cD];
        const float bE = b1[cE], bF = b1[cF], bG = b1[cG], bH = b1[cH];

        float cv0 = 0.f, cv1 = 0.f, cb0 = 0.f, cv0b = 0.f, cv1b = 0.f, cb0b = 0.f;
        const int f1 = rt - 200;
        if (rt >= 200) {
            cv0 = conv_w[f1]; cv1 = conv_w[FF + f1]; cb0 = conv_b[f1];
            if (f1 < 8) { cv0b = conv_w[56 + f1]; cv1b = conv_w[FF + 56 + f1]; cb0b = conv_b[56 + f1]; }
        }
        if (rt >= 200) {                               // x(0) into slot 0
            X1[f1] = (_Float16)fmaxf(fmaf(s_buf[0], cv0, fmaf(s_buf[1], cv1, cb0)), 0.f);
            if (f1 < 8)
                X1[56 + f1] = (_Float16)fmaxf(fmaf(s_buf[0], cv0b, fmaf(s_buf[1], cv1b, cb0b)), 0.f);
        }
        __syncthreads();                               // (B)

        float c0 = 0.0f, c1 = 0.0f;
        for (int t = 0; t <= TP; ++t) {
            if (t < TP) {
                _Float16* cur = X1 + (t & 1) * K1;
                _Float16* nx1 = X1 + ((t & 1) ^ 1) * K1;
                _Float16* x2n = X2 + ((t & 1) ^ 1) * K2;
                if (rt < 200) {
                    float zA = 0.f, zB = 0.f, zC = 0.f, zD = 0.f;
                    float zE = 0.f, zF = 0.f, zG = 0.f, zH = 0.f;
                    const float4* vb = (const float4*)(cur + kb);
                    DOT8(0, 0, 1, 2, 3)    DOT8(1, 4, 5, 6, 7)    DOT8(2, 8, 9, 10, 11)
                    DOT8(3, 12, 13, 14, 15) DOT8(4, 16, 17, 18, 19) DOT8(5, 20, 21, 22, 23)
                    const float zi0 = qsum4(zA) + bA, zf0 = qsum4(zB) + bB;
                    const float zg0 = qsum4(zC) + bC, zo0 = qsum4(zD) + bD;
                    const float zi1 = qsum4(zE) + bE, zf1 = qsum4(zF) + bF;
                    const float zg1 = qsum4(zG) + bG, zo1 = qsum4(zH) + bH;
                    c0 = fmaf(sig(zf0), c0, sig(zi0) * fmaxf(zg0, 0.f));
                    const float h0 = sig(zo0) * fmaxf(c0, 0.f);
                    c1 = fmaf(sig(zf1), c1, sig(zi1) * fmaxf(zg1, 0.f));
                    const float h1 = sig(zo1) * fmaxf(c1, 0.f);
                    if (sq == 0) {
                        const _Float16 hq = (_Float16)h0;
                        nx1[FF + q] = hq;              // h1 for LSTM1(t+1)
                        x2n[q]      = hq;              // x2 for LSTM2
                    } else if (sq == 1) {
                        const _Float16 hq = (_Float16)h1;
                        nx1[FF + 50 + q] = hq;
                        x2n[50 + q]      = hq;
                    }
                } else if (t + 1 < TP) {               // conv x(t+1) into next slot
                    nx1[f1] = (_Float16)fmaxf(fmaf(s_buf[t + 1], cv0, fmaf(s_buf[t + 2], cv1, cb0)), 0.f);
                    if (f1 < 8)
                        nx1[56 + f1] = (_Float16)fmaxf(fmaf(s_buf[t + 1], cv0b, fmaf(s_buf[t + 2], cv1b, cb0b)), 0.f);
                }
            }
            __syncthreads();                           // (C) one per step
        }
    } else {
        // ================= CONSUMER waves: LSTM2 + dense + softmax ==========
        const int rt  = tid - 256;
        const int q   = (rt < 200) ? (rt >> 2) : 0;
        const int sq  = rt & 3;
        const int cA = q,        cB = HH + q,       cC = 2*HH + q,      cD = 3*HH + q;
        const int cE = 50 + q,   cF = HH + 50 + q,  cG = 2*HH + 50 + q, cH = 3*HH + 50 + q;
        const float* W = w2;
        const float* U = u2;
        const int kb = sq * 56;                        // quarter base, 112 B aligned

        L28(DW8)
        L28(LWC8)
        const float bA = b2[cA], bB = b2[cB], bC = b2[cC], bD = b2[cD];
        const float bE = b2[cE], bF = b2[cF], bG = b2[cG], bH = b2[cH];
        __syncthreads();                               // (B)

        float c0 = 0.0f, c1 = 0.0f;
        for (int t = 0; t <= TP; ++t) {
            if (t >= 1 && rt < 200) {                  // consumer step t-1
                _Float16* cur = X2 + (t & 1) * K2;
                float zA = 0.f, zB = 0.f, zC = 0.f, zD = 0.f;
                float zE = 0.f, zF = 0.f, zG = 0.f, zH = 0.f;
                const float4* vb = (const float4*)(cur + kb);
                DOT8(0, 0, 1, 2, 3)    DOT8(1, 4, 5, 6, 7)    DOT8(2, 8, 9, 10, 11)
                DOT8(3, 12, 13, 14, 15) DOT8(4, 16, 17, 18, 19) DOT8(5, 20, 21, 22, 23)
                DOT8(6, 24, 25, 26, 27)
                const float zi0 = qsum4(zA) + bA, zf0 = qsum4(zB) + bB;
                const float zg0 = qsum4(zC) + bC, zo0 = qsum4(zD) + bD;
                const float zi1 = qsum4(zE) + bE, zf1 = qsum4(zF) + bF;
                const float zg1 = qsum4(zG) + bG, zo1 = qsum4(zH) + bH;
                c0 = fmaf(sig(zf0), c0, sig(zi0) * fmaxf(zg0, 0.f));
                const float h0 = sig(zo0) * fmaxf(c0, 0.f);
                c1 = fmaf(sig(zf1), c1, sig(zi1) * fmaxf(zg1, 0.f));
                const float h1 = sig(zo1) * fmaxf(c1, 0.f);
                if (sq == 0)      X2[((t & 1) ^ 1) * K2 + 112 + q]      = (_Float16)h0;
                else if (sq == 1) X2[((t & 1) ^ 1) * K2 + 112 + 50 + q] = (_Float16)h1;
            }
            __syncthreads();                           // (C) one per step
        }

        // final h2(TP-1) was written at iter TP into slot ((TP&1)^1)=0
        if (rt == 0) {
            float l[3];
#pragma unroll
            for (int a = 0; a < 3; ++a) {
                float acc = db[a];
                for (int j = 0; j < HH; ++j)
                    acc = fmaf((float)X2[112 + j], dw[j * 3 + a], acc);
                l[a] = acc;
            }
            const float m = fmaxf(l[0], fmaxf(l[1], l[2]));
            const float e0 = __expf(l[0] - m), e1 = __expf(l[1] - m), e2 = __expf(l[2] - m);
            const float inv = 1.0f / (e0 + e1 + e2);
            out[b * 3 + 0] = e0 * inv;
            out[b * 3 + 1] = e1 * inv;
            out[b * 3 + 2] = e2 * inv;
        }
    }
}

// ---------------- launch ----------------------------------------------------
extern "C" void kernel_launch(void* const* d_in, const int* in_sizes, int n_in,
                              void* d_out, int out_size, void* d_ws, size_t ws_size,
                              hipStream_t stream) {
    const float* s      = (const float*)d_in[0];
    const float* conv_w = (const float*)d_in[1];
    const float* conv_b = (const float*)d_in[2];
    const float* w1     = (const float*)d_in[3];
    const float* u1     = (const float*)d_in[4];
    const float* b1     = (const float*)d_in[5];
    const float* w2     = (const float*)d_in[6];
    const float* u2     = (const float*)d_in[7];
    const float* b2     = (const float*)d_in[8];
    const float* dw     = (const float*)d_in[9];
    const float* db     = (const float*)d_in[10];

    fused_lstm_kernel<<<BB, 512, 0, stream>>>(
        s, conv_w, conv_b, w1, u1, b1, w2, u2, b2, dw, db, (float*)d_out);
}

// Round 2
// 2747.835 us; speedup vs baseline: 1.1387x; 1.1387x over previous
//
#include <hip/hip_runtime.h>
#include <math.h>

// Conv1D(k=2,F=64,relu) -> LSTM1(H=100, relu cell, seq) -> LSTM2 (last) ->
// Dense(3) -> softmax.  B=128, T=2048, T'=2047.
//
// Round-7 design (recovery from round-6 spill regression):
//  * PRODUCER keeps round-6's Op=8 quad-split (2 units x 4 gates per thread,
//    4-way K split, K1=192, 6 ds_read_b128/thread, 192 weight h2 regs) --
//    verified correct in round 6 and fits the register budget (~215).
//  * CONSUMER reverts to round-5's Op=4 pair-split (1 unit x 4 gates, 2-way
//    K split, K2=208, 200 weight h2 regs) -- round-6's Op=8 consumer needed
//    224 weight regs + misc ~= 250 > budget -> scratch spill in the step
//    loop (FETCH 10.9->26.7 MB, WRITE 15.7->46 MB, +26% time).
//  * ALL cross-lane reductions use DPP quad_perm (pure VALU: xor-1 = 0xB1,
//    xor-2 = 0x4E) instead of ds_swizzle -- removes 32 DS wave-insts/step
//    and ~120 cyc of serial DS latency from the per-step tail.
//  * Everything else as round 5/6: one block per batch element, waves 0..3
//    conv+LSTM1 (producer), waves 4..7 LSTM2 one step behind (consumer),
//    2-slot LDS rings, one barrier per step, weights resident in h2 regs.

typedef _Float16 h2 __attribute__((ext_vector_type(2)));

#define BB 128
#define TT 2048
#define TP 2047
#define HH 100
#define G4 400
#define FF 64

#define K1 192   // producer combined-K halves (x 64 + h1 100 + pad 28)
#define K2 208   // consumer combined-K halves (x2 100 + gap 4 + h2 100 + pad 4)

#define L24(X) X(0) X(1) X(2) X(3) X(4) X(5) X(6) X(7) X(8) X(9) \
 X(10) X(11) X(12) X(13) X(14) X(15) X(16) X(17) X(18) X(19) \
 X(20) X(21) X(22) X(23)
#define L50(X) L24(X) X(24) X(25) X(26) X(27) X(28) X(29) \
 X(30) X(31) X(32) X(33) X(34) X(35) X(36) X(37) X(38) X(39) \
 X(40) X(41) X(42) X(43) X(44) X(45) X(46) X(47) X(48) X(49)

// ---------------- producer (Op=8) weight machinery --------------------------
#define DW8(i) h2 wA##i, wB##i, wC##i, wD##i, wE##i, wF##i, wG##i, wH##i;

// producer combined column: K = [conv-x(64) ; U(100) ; pad(28)] -> 192
static __device__ __forceinline__ _Float16 pw(const float* __restrict__ W,
                                              const float* __restrict__ U,
                                              int c, int k) {
    float v = (k < FF) ? W[k * G4 + c] : (k < FF + HH ? U[(k - FF) * G4 + c] : 0.0f);
    return (_Float16)v;
}

#define LWP8(i) { const int k = kb + 2 * (i); \
  wA##i = h2{pw(W,U,cA,k), pw(W,U,cA,k+1)}; \
  wB##i = h2{pw(W,U,cB,k), pw(W,U,cB,k+1)}; \
  wC##i = h2{pw(W,U,cC,k), pw(W,U,cC,k+1)}; \
  wD##i = h2{pw(W,U,cD,k), pw(W,U,cD,k+1)}; \
  wE##i = h2{pw(W,U,cE,k), pw(W,U,cE,k+1)}; \
  wF##i = h2{pw(W,U,cF,k), pw(W,U,cF,k+1)}; \
  wG##i = h2{pw(W,U,cG,k), pw(W,U,cG,k+1)}; \
  wH##i = h2{pw(W,U,cH,k), pw(W,U,cH,k+1)}; }

// ---------------- consumer (Op=4) weight machinery --------------------------
#define DW4(q) h2 wa##q, wb##q, wc##q, wd##q;

// consumer combined column: K = [W(100) ; gap(4) ; U(100) ; pad(4)] -> 208
// (even lane queries k in [0,100), odd lane k in [104,204))
static __device__ __forceinline__ _Float16 cwf(const float* __restrict__ W,
                                               const float* __restrict__ U,
                                               int c, int k) {
    float v = (k < HH) ? W[k * G4 + c] : U[(k - 104) * G4 + c];
    return (_Float16)v;
}

#define LWC4(q) { const int k = kb + 2 * (q); \
  wa##q = h2{cwf(W,U,cA,k), cwf(W,U,cA,k+1)}; \
  wb##q = h2{cwf(W,U,cB,k), cwf(W,U,cB,k+1)}; \
  wc##q = h2{cwf(W,U,cC,k), cwf(W,U,cC,k+1)}; \
  wd##q = h2{cwf(W,U,cD,k), cwf(W,U,cD,k+1)}; }

// ---------------- dot kernels ----------------------------------------------
#define FD(w, x, acc) acc = __builtin_amdgcn_fdot2(w, x, acc, false)
#define B2(f) __builtin_bit_cast(h2, f)

// producer: one float4 operand chunk feeds 8 dot chains (2 units x 4 gates)
#define DOT8X(vs, i) { const h2 xx = B2(vs); \
  FD(wA##i, xx, zA); FD(wB##i, xx, zB); FD(wC##i, xx, zC); FD(wD##i, xx, zD); \
  FD(wE##i, xx, zE); FD(wF##i, xx, zF); FD(wG##i, xx, zG); FD(wH##i, xx, zH); }
#define DOT8(r, a0, a1, a2, a3) { const float4 v = vb[r]; \
  DOT8X(v.x, a0) DOT8X(v.y, a1) DOT8X(v.z, a2) DOT8X(v.w, a3) }

// consumer: one float4 chunk feeds 4 dot chains (1 unit x 4 gates)
#define DOT4(r, q0, q1, q2, q3) { const float4 v = vb[r]; \
  const h2 x0 = B2(v.x), x1 = B2(v.y), x2 = B2(v.z), x3 = B2(v.w); \
  FD(wa##q0, x0, zA0); FD(wb##q0, x0, zB0); FD(wc##q0, x0, zC0); FD(wd##q0, x0, zD0); \
  FD(wa##q1, x1, zA1); FD(wb##q1, x1, zB1); FD(wc##q1, x1, zC1); FD(wd##q1, x1, zD1); \
  FD(wa##q2, x2, zA0); FD(wb##q2, x2, zB0); FD(wc##q2, x2, zC0); FD(wd##q2, x2, zD0); \
  FD(wa##q3, x3, zA1); FD(wb##q3, x3, zB1); FD(wc##q3, x3, zC1); FD(wd##q3, x3, zD1); }

#define DOTT(q0, q1) { const float2 v = *tb; \
  const h2 x0 = B2(v.x), x1 = B2(v.y); \
  FD(wa##q0, x0, zA0); FD(wb##q0, x0, zB0); FD(wc##q0, x0, zC0); FD(wd##q0, x0, zD0); \
  FD(wa##q1, x1, zA1); FD(wb##q1, x1, zB1); FD(wc##q1, x1, zC1); FD(wd##q1, x1, zD1); }

// ---------------- cross-lane reductions (DPP, no DS pipe) -------------------
// 4-lane quad butterfly sum: 0xB1 = quad_perm [1,0,3,2] (xor 1),
// 0x4E = quad_perm [2,3,0,1] (xor 2).  All 4 lanes end bitwise-identical.
static __device__ __forceinline__ float qsum4(float z) {
    int p1 = __builtin_amdgcn_update_dpp(0, __builtin_bit_cast(int, z),
                                         0xB1, 0xF, 0xF, true);
    float s1 = z + __builtin_bit_cast(float, p1);
    int p2 = __builtin_amdgcn_update_dpp(0, __builtin_bit_cast(int, s1),
                                         0x4E, 0xF, 0xF, true);
    return s1 + __builtin_bit_cast(float, p2);
}
// lane-pair sum (xor-1); pairs (2p,2p+1) never straddle a quad.
static __device__ __forceinline__ float psum2(float z) {
    int p1 = __builtin_amdgcn_update_dpp(0, __builtin_bit_cast(int, z),
                                         0xB1, 0xF, 0xF, true);
    return z + __builtin_bit_cast(float, p1);
}
static __device__ __forceinline__ float sig(float z) {
    return 1.0f / (1.0f + __expf(-z));
}

__global__ __launch_bounds__(512, 2)
void fused_lstm_kernel(const float* __restrict__ s,       // [B,T]
                       const float* __restrict__ conv_w,  // [2,1,F]
                       const float* __restrict__ conv_b,  // [F]
                       const float* __restrict__ w1, const float* __restrict__ u1,
                       const float* __restrict__ b1,
                       const float* __restrict__ w2, const float* __restrict__ u2,
                       const float* __restrict__ b2,
                       const float* __restrict__ dw, const float* __restrict__ db,
                       float* __restrict__ out)           // [B,3]
{
    const int tid = threadIdx.x;
    const int b   = blockIdx.x;

    __shared__ float s_buf[TT];                        // 8 KB input row
    __shared__ __align__(16) _Float16 X1[2 * K1];      // producer operand ring
    __shared__ __align__(16) _Float16 X2[2 * K2];      // consumer operand ring

    for (int i = tid; i < TT; i += 512) s_buf[i] = s[(size_t)b * TT + i];
    if (tid < 2 * K1) X1[tid] = (_Float16)0.0f;        // pads stay 0 forever
    if (tid < 2 * K2) X2[tid] = (_Float16)0.0f;
    __syncthreads();                                   // (A)

    if (tid < 256) {
        // ================= PRODUCER waves: conv + LSTM1 (Op=8) ==============
        const int rt  = tid;
        const int q   = (rt < 200) ? (rt >> 2) : 0;    // unit pair {q, q+50}
        const int sq  = rt & 3;                        // K-quarter
        const int cA = q,        cB = HH + q,       cC = 2*HH + q,      cD = 3*HH + q;
        const int cE = 50 + q,   cF = HH + 50 + q,  cG = 2*HH + 50 + q, cH = 3*HH + 50 + q;
        const float* W = w1;
        const float* U = u1;
        const int kb = sq * 48;                        // quarter base, 96 B aligned

        L24(DW8)
        L24(LWP8)
        const float bA = b1[cA], bB = b1[cB], bC = b1[cC], bD = b1[cD];
        const float bE = b1[cE], bF = b1[cF], bG = b1[cG], bH = b1[cH];

        float cv0 = 0.f, cv1 = 0.f, cb0 = 0.f, cv0b = 0.f, cv1b = 0.f, cb0b = 0.f;
        const int f1 = rt - 200;
        if (rt >= 200) {
            cv0 = conv_w[f1]; cv1 = conv_w[FF + f1]; cb0 = conv_b[f1];
            if (f1 < 8) { cv0b = conv_w[56 + f1]; cv1b = conv_w[FF + 56 + f1]; cb0b = conv_b[56 + f1]; }
        }
        if (rt >= 200) {                               // x(0) into slot 0
            X1[f1] = (_Float16)fmaxf(fmaf(s_buf[0], cv0, fmaf(s_buf[1], cv1, cb0)), 0.f);
            if (f1 < 8)
                X1[56 + f1] = (_Float16)fmaxf(fmaf(s_buf[0], cv0b, fmaf(s_buf[1], cv1b, cb0b)), 0.f);
        }
        __syncthreads();                               // (B)

        float c0 = 0.0f, c1 = 0.0f;
        for (int t = 0; t <= TP; ++t) {
            if (t < TP) {
                _Float16* cur = X1 + (t & 1) * K1;
                _Float16* nx1 = X1 + ((t & 1) ^ 1) * K1;
                _Float16* x2n = X2 + ((t & 1) ^ 1) * K2;
                if (rt < 200) {
                    float zA = 0.f, zB = 0.f, zC = 0.f, zD = 0.f;
                    float zE = 0.f, zF = 0.f, zG = 0.f, zH = 0.f;
                    const float4* vb = (const float4*)(cur + kb);
                    DOT8(0, 0, 1, 2, 3)    DOT8(1, 4, 5, 6, 7)    DOT8(2, 8, 9, 10, 11)
                    DOT8(3, 12, 13, 14, 15) DOT8(4, 16, 17, 18, 19) DOT8(5, 20, 21, 22, 23)
                    const float zi0 = qsum4(zA) + bA, zf0 = qsum4(zB) + bB;
                    const float zg0 = qsum4(zC) + bC, zo0 = qsum4(zD) + bD;
                    const float zi1 = qsum4(zE) + bE, zf1 = qsum4(zF) + bF;
                    const float zg1 = qsum4(zG) + bG, zo1 = qsum4(zH) + bH;
                    c0 = fmaf(sig(zf0), c0, sig(zi0) * fmaxf(zg0, 0.f));
                    const float h0 = sig(zo0) * fmaxf(c0, 0.f);
                    c1 = fmaf(sig(zf1), c1, sig(zi1) * fmaxf(zg1, 0.f));
                    const float h1 = sig(zo1) * fmaxf(c1, 0.f);
                    if (sq == 0) {
                        const _Float16 hq = (_Float16)h0;
                        nx1[FF + q] = hq;              // h1 for LSTM1(t+1)
                        x2n[q]      = hq;              // x2 for LSTM2
                    } else if (sq == 1) {
                        const _Float16 hq = (_Float16)h1;
                        nx1[FF + 50 + q] = hq;
                        x2n[50 + q]      = hq;
                    }
                } else if (t + 1 < TP) {               // conv x(t+1) into next slot
                    nx1[f1] = (_Float16)fmaxf(fmaf(s_buf[t + 1], cv0, fmaf(s_buf[t + 2], cv1, cb0)), 0.f);
                    if (f1 < 8)
                        nx1[56 + f1] = (_Float16)fmaxf(fmaf(s_buf[t + 1], cv0b, fmaf(s_buf[t + 2], cv1b, cb0b)), 0.f);
                }
            }
            __syncthreads();                           // (C) one per step
        }
    } else {
        // ================= CONSUMER waves: LSTM2 + dense + softmax (Op=4) ===
        const int rt  = tid - 256;
        const int p   = (rt < 200) ? (rt >> 1) : 0;    // unit
        const int odd = rt & 1;                        // K-half
        const int cA = p, cB = HH + p, cC = 2 * HH + p, cD = 3 * HH + p;
        const float* W = w2;
        const float* U = u2;
        const int kb = odd ? 104 : 0;                  // K-half base (halves)

        L50(DW4)
        L50(LWC4)
        const float biA = b2[cA], biB = b2[cB], biC = b2[cC], biD = b2[cD];
        __syncthreads();                               // (B)

        float c = 0.0f;
        for (int t = 0; t <= TP; ++t) {
            if (t >= 1 && rt < 200) {                  // consumer step t-1
                _Float16* cur = X2 + (t & 1) * K2;
                float zA0 = 0.f, zA1 = 0.f, zB0 = 0.f, zB1 = 0.f;
                float zC0 = 0.f, zC1 = 0.f, zD0 = 0.f, zD1 = 0.f;
                const float4* vb = (const float4*)(cur + kb);
                DOT4(0,0,1,2,3)     DOT4(1,4,5,6,7)     DOT4(2,8,9,10,11)
                DOT4(3,12,13,14,15) DOT4(4,16,17,18,19) DOT4(5,20,21,22,23)
                DOT4(6,24,25,26,27) DOT4(7,28,29,30,31) DOT4(8,32,33,34,35)
                DOT4(9,36,37,38,39) DOT4(10,40,41,42,43) DOT4(11,44,45,46,47)
                const float2* tb = (const float2*)(cur + kb + 96);
                DOTT(48, 49)
                const float zi = psum2(zA0 + zA1) + biA;
                const float zf = psum2(zB0 + zB1) + biB;
                const float zg = psum2(zC0 + zC1) + biC;
                const float zo = psum2(zD0 + zD1) + biD;
                const float gi = sig(zi), gf = sig(zf), go = sig(zo);
                const float gg = fmaxf(zg, 0.f);
                c = fmaf(gf, c, gi * gg);
                const float h = go * fmaxf(c, 0.f);
                if (odd) X2[((t & 1) ^ 1) * K2 + 104 + p] = (_Float16)h;
            }
            __syncthreads();                           // (C) one per step
        }

        // final h2(TP-1) was written at iter TP into slot ((TP&1)^1)=0
        if (rt == 0) {
            float l[3];
#pragma unroll
            for (int a = 0; a < 3; ++a) {
                float acc = db[a];
                for (int j = 0; j < HH; ++j)
                    acc = fmaf((float)X2[104 + j], dw[j * 3 + a], acc);
                l[a] = acc;
            }
            const float m = fmaxf(l[0], fmaxf(l[1], l[2]));
            const float e0 = __expf(l[0] - m), e1 = __expf(l[1] - m), e2 = __expf(l[2] - m);
            const float inv = 1.0f / (e0 + e1 + e2);
            out[b * 3 + 0] = e0 * inv;
            out[b * 3 + 1] = e1 * inv;
            out[b * 3 + 2] = e2 * inv;
        }
    }
}

// ---------------- launch ----------------------------------------------------
extern "C" void kernel_launch(void* const* d_in, const int* in_sizes, int n_in,
                              void* d_out, int out_size, void* d_ws, size_t ws_size,
                              hipStream_t stream) {
    const float* s      = (const float*)d_in[0];
    const float* conv_w = (const float*)d_in[1];
    const float* conv_b = (const float*)d_in[2];
    const float* w1     = (const float*)d_in[3];
    const float* u1     = (const float*)d_in[4];
    const float* b1     = (const float*)d_in[5];
    const float* w2     = (const float*)d_in[6];
    const float* u2     = (const float*)d_in[7];
    const float* b2     = (const float*)d_in[8];
    const float* dw     = (const float*)d_in[9];
    const float* db     = (const float*)d_in[10];

    fused_lstm_kernel<<<BB, 512, 0, stream>>>(
        s, conv_w, conv_b, w1, u1, b1, w2, u2, b2, dw, db, (float*)d_out);
}